// Round 14
// baseline (107.148 us; speedup 1.0000x reference)
//
#include <hip/hip_runtime.h>

typedef float f32x4 __attribute__((ext_vector_type(4)));
typedef short short8 __attribute__((ext_vector_type(8)));
typedef short s16x4 __attribute__((ext_vector_type(4)));

#define N_TOT 1024
#define N_HALF 512
#define D 64
#define KPOOL 256

#if __has_builtin(__builtin_amdgcn_exp2f)
#define EXP2F(x) __builtin_amdgcn_exp2f(x)
#else
#define EXP2F(x) __expf((x) * 0.6931471805599453f)
#endif
#if __has_builtin(__builtin_amdgcn_rcpf)
#define RCPF(x) __builtin_amdgcn_rcpf(x)
#else
#define RCPF(x) (1.0f / (x))
#endif

__device__ __forceinline__ short f2bf(float v) {
    unsigned u = __float_as_uint(v);
    u += 0x7FFFu + ((u >> 16) & 1u);   // round-to-nearest-even
    return (short)(u >> 16);
}
__device__ __forceinline__ float bf2f(unsigned short u) {
    return __uint_as_float(((unsigned)u) << 16);
}

// ---------------- Kernel 1: x = concat(x1@W1+b1, x2@W2+b2); 4 rows/block, vectorized xT writes
__global__ void __launch_bounds__(64)
k_proj(const float* __restrict__ x1, const float* __restrict__ x2,
       const float* __restrict__ W1, const float* __restrict__ b1,
       const float* __restrict__ W2, const float* __restrict__ b2,
       float* __restrict__ x_f, unsigned short* __restrict__ x_bf,
       unsigned short* __restrict__ xT_hi, unsigned short* __restrict__ xT_lo) {
    int blk = blockIdx.x;             // 512 = b(2) x 256 row-groups of 4
    int b = blk >> 8;
    int n0 = (blk & 255) * 4;
    int t = threadIdx.x;

    const float *src, *W, *bias;
    if (n0 < N_HALF) { src = x1 + (b * N_HALF + n0) * D;            W = W1; bias = b1; }
    else             { src = x2 + (b * N_HALF + (n0 - N_HALF)) * D; W = W2; bias = b2; }

    __shared__ float rows[4][D];
#pragma unroll
    for (int r = 0; r < 4; ++r) rows[r][t] = src[r * D + t];
    __syncthreads();

    float bv = bias[t];
    float acc[4];
#pragma unroll
    for (int r = 0; r < 4; ++r) acc[r] = bv;
    for (int d = 0; d < D; ++d) {
        float w = W[d * D + t];
#pragma unroll
        for (int r = 0; r < 4; ++r) acc[r] = fmaf(rows[r][d], w, acc[r]);
    }

    s16x4 hiv, lov;
#pragma unroll
    for (int r = 0; r < 4; ++r) {
        unsigned short hi = (unsigned short)f2bf(acc[r]);
        unsigned short lo = (unsigned short)f2bf(acc[r] - bf2f(hi));
        x_f[((size_t)b * N_TOT + n0 + r) * D + t] = acc[r];
        x_bf[((size_t)b * N_TOT + n0 + r) * D + t] = hi;
        hiv[r] = (short)hi; lov[r] = (short)lo;
    }
    *reinterpret_cast<s16x4*>(xT_hi + ((size_t)b * D + t) * N_TOT + n0) = hiv;
    *reinterpret_cast<s16x4*>(xT_lo + ((size_t)b * D + t) * N_TOT + n0) = lov;
}

// ---------------- Kernel 2: scores, upper triangle only (s symmetric), E packed (hi<<16|lo)
// grid 2048, work-balance swizzle; bias pre-loaded into MFMA accumulator, C2 folded into bfrag
__global__ void __launch_bounds__(256)
k_score(const float* __restrict__ x_f, const unsigned short* __restrict__ x_bf,
        const float* __restrict__ Wa, const float* __restrict__ ba,
        const float* __restrict__ w11, const float* __restrict__ w22,
        const float* __restrict__ w12, unsigned* __restrict__ Ep) {
    int bid = blockIdx.x;             // 0..2047
    int b = bid >> 10, n = bid & 1023;
    int q = n >> 8, c = n & 255;
    int i = (q << 8) | ((q & 1) ? (255 - c) : c);
    int tid = threadIdx.x;
    int l = tid & 63, wv = tid >> 6;
    int kc = l & 15, dg = l >> 4;

    __shared__ float xi_s[D];
    if (tid < D) xi_s[tid] = x_f[(b * N_TOT + i) * D + tid];
    __syncthreads();

    const float C2 = 2.885390081777927f;      // 2*log2(e)
    const float LOG2E = 1.4426950408889634f;

    const float* wTop = (i < N_HALF) ? w11 : w12;   // weight when j < 512
    const float* wBot = (i < N_HALF) ? w12 : w22;   // weight when j >= 512

    // B fragments: B[d][k] = x_i[d] * Wa[d][k] * C2 in bf16 (C2 folded);
    // MFMA accumulator initialized with ba[k]*C2 -> exp2(acc) directly.
    short8 bfrag[4][2];
    f32x4 accinit[4];
    float wm2A[4], wm2B[4];
    float wsumA = 0.f, wsumB = 0.f;
#pragma unroll
    for (int kt = 0; kt < 4; ++kt) {
        int kcol = kt * 16 + kc;
        float bac = ba[kcol] * C2;
        accinit[kt] = {bac, bac, bac, bac};   // col = kc constant per lane
        float wA = wTop[kcol], wB = wBot[kcol];
        wm2A[kt] = -2.f * wA; wm2B[kt] = -2.f * wB;
        wsumA += wA; wsumB += wB;
#pragma unroll
        for (int mm = 0; mm < 2; ++mm) {
            short8 f;
#pragma unroll
            for (int e = 0; e < 8; ++e) {
                int d = mm * 32 + dg * 8 + e;
                f[e] = f2bf(xi_s[d] * Wa[d * D + kcol] * C2);
            }
            bfrag[kt][mm] = f;
        }
    }

    const unsigned short* xb_b = x_bf + b * N_TOT * D;
    unsigned* Eb = Ep + ((size_t)b << 20);
    int jt0 = i >> 4;
    for (int jt = jt0 + wv; jt < 64; jt += 4) {
        const unsigned short* arow = xb_b + (jt * 16 + kc) * D + dg * 8;
        short8 a0 = *reinterpret_cast<const short8*>(arow);
        short8 a1 = *reinterpret_cast<const short8*>(arow + 32);
        f32x4 acc[4];
#pragma unroll
        for (int kt = 0; kt < 4; ++kt) {
            f32x4 z = accinit[kt];
            z = __builtin_amdgcn_mfma_f32_16x16x32_bf16(a0, bfrag[kt][0], z, 0, 0, 0);
            z = __builtin_amdgcn_mfma_f32_16x16x32_bf16(a1, bfrag[kt][1], z, 0, 0, 0);
            acc[kt] = z;
        }
        bool top = (jt < 32);
        float wsum_t = top ? wsumA : wsumB;
        float wm2s[4];
#pragma unroll
        for (int kt = 0; kt < 4; ++kt) wm2s[kt] = top ? wm2A[kt] : wm2B[kt];
#pragma unroll
        for (int r = 0; r < 4; ++r) {
            float part = wsum_t;
#pragma unroll
            for (int kt = 0; kt < 4; ++kt) {
                float e2 = EXP2F(acc[kt][r]);
                float rcv = RCPF(e2 + 1.f);
                part = fmaf(wm2s[kt], rcv, part);
            }
            part += __shfl_xor(part, 1);
            part += __shfl_xor(part, 2);
            part += __shfl_xor(part, 4);
            part += __shfl_xor(part, 8);
            if (kc == 0) {
                int j = jt * 16 + dg * 4 + r;
                if (j >= i) {
                    float e = EXP2F(part * LOG2E);   // |s| <= sum|w| ~ 10, no max-shift
                    unsigned short eh = (unsigned short)f2bf(e);
                    unsigned short el = (unsigned short)f2bf(e - bf2f(eh));
                    unsigned pk = ((unsigned)eh << 16) | (unsigned)el;
                    Eb[(size_t)i * N_TOT + j] = pk;
                    if (j > i) Eb[(size_t)j * N_TOT + i] = pk;
                }
            }
        }
    }
}

// ---------------- Kernel 3: partial agg via hi/lo MFMA over j-halves of 512, + rowsum partials
__global__ void __launch_bounds__(256)
k_aggp(const unsigned* __restrict__ Ep,
       const unsigned short* __restrict__ xT_hi, const unsigned short* __restrict__ xT_lo,
       float* __restrict__ pagg, float* __restrict__ rowsum_part) {
    int blk = blockIdx.x;             // 256 = b(2) x it(64) x jh(2)
    int b = blk >> 7, rest = blk & 127;
    int it = rest >> 1, jh = rest & 1;
    int i0 = it * 16, jbase = jh * 512;
    int tid = threadIdx.x;
    int l = tid & 63, wv = tid >> 6;
    int kc = l & 15, dg = l >> 4;

    const unsigned* Eb = Ep + ((size_t)b << 20);
    const unsigned short* xTH = xT_hi + (size_t)b * D * N_TOT;
    const unsigned short* xTL = xT_lo + (size_t)b * D * N_TOT;

    f32x4 C0 = {0.f, 0.f, 0.f, 0.f}, C1 = C0, C2v = C0;
    const unsigned* Ap = Eb + (size_t)(i0 + kc) * N_TOT + jbase + dg * 8;
    const unsigned short* BH = xTH + (size_t)(wv * 16 + kc) * N_TOT + jbase + dg * 8;
    const unsigned short* BL = xTL + (size_t)(wv * 16 + kc) * N_TOT + jbase + dg * 8;
#pragma unroll 4
    for (int ks = 0; ks < 16; ++ks) {
        uint4 p0 = *reinterpret_cast<const uint4*>(Ap + ks * 32);
        uint4 p1 = *reinterpret_cast<const uint4*>(Ap + ks * 32 + 4);
        short8 ah, al;
        ah[0] = (short)(p0.x >> 16); al[0] = (short)(p0.x & 0xffff);
        ah[1] = (short)(p0.y >> 16); al[1] = (short)(p0.y & 0xffff);
        ah[2] = (short)(p0.z >> 16); al[2] = (short)(p0.z & 0xffff);
        ah[3] = (short)(p0.w >> 16); al[3] = (short)(p0.w & 0xffff);
        ah[4] = (short)(p1.x >> 16); al[4] = (short)(p1.x & 0xffff);
        ah[5] = (short)(p1.y >> 16); al[5] = (short)(p1.y & 0xffff);
        ah[6] = (short)(p1.z >> 16); al[6] = (short)(p1.z & 0xffff);
        ah[7] = (short)(p1.w >> 16); al[7] = (short)(p1.w & 0xffff);
        short8 bh = *reinterpret_cast<const short8*>(BH + ks * 32);
        short8 bl = *reinterpret_cast<const short8*>(BL + ks * 32);
        C0 = __builtin_amdgcn_mfma_f32_16x16x32_bf16(ah, bh, C0, 0, 0, 0);
        C1 = __builtin_amdgcn_mfma_f32_16x16x32_bf16(ah, bl, C1, 0, 0, 0);
        C2v = __builtin_amdgcn_mfma_f32_16x16x32_bf16(al, bh, C2v, 0, 0, 0);
    }
    f32x4 C = (C0 + C1) + C2v;

    // rowsum partial: wave wv rows wv*4..wv*4+3, 16 segs of 32 j, both halves of packed
    {
        int row = wv * 4 + (l & 3);
        int seg = l >> 2;
        const unsigned* Er = Eb + (size_t)(i0 + row) * N_TOT + jbase + seg * 32;
        float rs = 0.f;
#pragma unroll
        for (int u = 0; u < 8; ++u) {
            uint4 v = *reinterpret_cast<const uint4*>(Er + u * 4);
            rs += __uint_as_float(v.x & 0xffff0000u) + __uint_as_float(v.x << 16);
            rs += __uint_as_float(v.y & 0xffff0000u) + __uint_as_float(v.y << 16);
            rs += __uint_as_float(v.z & 0xffff0000u) + __uint_as_float(v.z << 16);
            rs += __uint_as_float(v.w & 0xffff0000u) + __uint_as_float(v.w << 16);
        }
        rs += __shfl_xor(rs, 4);
        rs += __shfl_xor(rs, 8);
        rs += __shfl_xor(rs, 16);
        rs += __shfl_xor(rs, 32);
        if (l < 4) rowsum_part[(size_t)(b * 2 + jh) * N_TOT + i0 + wv * 4 + l] = rs;
    }

#pragma unroll
    for (int r = 0; r < 4; ++r)
        pagg[((size_t)(b * 2 + jh) * N_TOT + i0 + dg * 4 + r) * D + wv * 16 + kc] = C[r];
}

// ---------------- Kernel 4: finish agg (+rinv), xo = agg@Wpa + x@Wwoa + biases, BN partials
__global__ void __launch_bounds__(256)
k_aggfin(const float* __restrict__ pagg, const float* __restrict__ rowsum_part,
         const float* __restrict__ x_f,
         const float* __restrict__ Wpa, const float* __restrict__ bpa,
         const float* __restrict__ Wwoa, const float* __restrict__ bwoa,
         float* __restrict__ xo_pre, float* __restrict__ partials) {
    int b = blockIdx.x >> 6, it = blockIdx.x & 63;
    int i0 = it * 16;
    int tid = threadIdx.x;
    int l = tid & 63, wv = tid >> 6;

    __shared__ float aggL[16][D];
    __shared__ float xiL[16][D];
    __shared__ float xoL[16][D];
    __shared__ float riL[16];

    const float* p0 = pagg + ((size_t)(b * 2 + 0) * N_TOT + i0) * D;
    const float* p1 = pagg + ((size_t)(b * 2 + 1) * N_TOT + i0) * D;
    const float* xB = x_f + ((size_t)b * N_TOT + i0) * D;
#pragma unroll
    for (int u = 0; u < 4; ++u) {
        int idx = tid + u * 256;       // 0..1023 = row*64+k
        reinterpret_cast<float*>(aggL)[idx] = p0[idx] + p1[idx];
        reinterpret_cast<float*>(xiL)[idx] = xB[idx];
    }
    if (tid < 16)
        riL[tid] = 1.f / (rowsum_part[(size_t)(b * 2 + 0) * N_TOT + i0 + tid] +
                          rowsum_part[(size_t)(b * 2 + 1) * N_TOT + i0 + tid]);
    __syncthreads();
#pragma unroll
    for (int u = 0; u < 4; ++u) {
        int idx = tid + u * 256;
        reinterpret_cast<float*>(aggL)[idx] *= riL[idx >> 6];
    }
    __syncthreads();

    int k = l;
    float xo[4];
#pragma unroll
    for (int r = 0; r < 4; ++r) xo[r] = bpa[k] + bwoa[k];
    for (int dd = 0; dd < D; ++dd) {
        float wp = Wpa[dd * D + k], ww = Wwoa[dd * D + k];
#pragma unroll
        for (int r = 0; r < 4; ++r) {
            int row = wv * 4 + r;
            xo[r] += aggL[row][dd] * wp + xiL[row][dd] * ww;
        }
    }
#pragma unroll
    for (int r = 0; r < 4; ++r) {
        int row = wv * 4 + r;
        xo_pre[((size_t)b * N_TOT + i0 + row) * D + k] = xo[r];
        xoL[row][k] = xo[r];
    }
    __syncthreads();
    if (tid < D) {
        float s = 0.f, qv = 0.f;
#pragma unroll
        for (int mm = 0; mm < 16; ++mm) { float v = xoL[mm][tid]; s += v; qv = fmaf(v, v, qv); }
        partials[blockIdx.x * 128 + tid] = s;
        partials[blockIdx.x * 128 + 64 + tid] = qv;
    }
}

// ---------------- Kernel 5: fused BN-stats + scores + top-k + gather (4 blocks x 1024)
__global__ void __launch_bounds__(1024)
k_tail(const float* __restrict__ xo_pre, const float* __restrict__ partials,
       const float* __restrict__ gamma, const float* __restrict__ beta,
       const float* __restrict__ Wp, const float* __restrict__ bp,
       float* __restrict__ out) {
    int b = blockIdx.x >> 1, half = blockIdx.x & 1;
    int t = threadIdx.x;            // 1024
    int d = t & 63;
    int wvg = t >> 6;               // wave id 0..15

    __shared__ float SQ[8][128];
    __shared__ float muL[D], rsL[D];
    __shared__ float sc_s[N_HALF];
    __shared__ unsigned long long keys[N_HALF];
    __shared__ unsigned short map[KPOOL];

    // --- P1: BN stats from 128 partial blocks
    {
        int g = t >> 7, f = t & 127;     // g 0..7
        float s = 0.f;
        for (int blk = g; blk < 128; blk += 8) s += partials[blk * 128 + f];
        SQ[g][f] = s;
        __syncthreads();
        if (t < 128) {
            float tot = 0.f;
#pragma unroll
            for (int g2 = 0; g2 < 8; ++g2) tot += SQ[g2][t];
            SQ[0][t] = tot;
        }
        __syncthreads();
        if (t < D) {
            float mu = SQ[0][t] * (1.f / 2048.f);
            float ex2 = SQ[0][64 + t] * (1.f / 2048.f);
            muL[t] = mu;
            rsL[t] = rsqrtf(ex2 - mu * mu + 1e-5f);
        }
        __syncthreads();
    }

    const float kScale = 1.0507009873554805f, kAlpha = 1.6732632423543772f;
    int base = b * N_TOT + half * N_HALF;
    float mu = muL[d], rs = rsL[d], gm = gamma[d], bt = beta[d], wp = Wp[d];
    float bpv = bp[0];

    // --- P2: scores for 512 rows; wave wvg handles rows wvg*32 .. wvg*32+31
    for (int u = 0; u < 32; ++u) {
        int r = wvg * 32 + u;
        float v = xo_pre[(size_t)(base + r) * D + d];
        v = (v - mu) * rs * gm + bt;
        v = (v > 0.f) ? kScale * v : kScale * kAlpha * expm1f(v);
        float pd = v * wp;
#pragma unroll
        for (int off = 32; off >= 1; off >>= 1) pd += __shfl_xor(pd, off);
        if (d == 0) {
            float sc = 1.f / (1.f + __expf(-(pd + bpv)));
            sc_s[r] = sc;
            keys[r] = ((unsigned long long)__float_as_uint(sc) << 10) | (unsigned)(511 - r);
        }
    }
    __syncthreads();

    // --- P3: exact rank of 512 keys (threads 0..511)
    if (t < N_HALF) {
        unsigned long long mine = keys[t];
        int cnt = 0;
#pragma unroll 8
        for (int qq = 0; qq < N_HALF; ++qq) cnt += (keys[qq] > mine) ? 1 : 0;
        if (cnt < KPOOL) map[cnt] = (unsigned short)t;
    }
    __syncthreads();

    // --- P4: gather 256 selected rows, re-normalize, scale, write out
    for (int u = 0; u < 16; ++u) {
        int rr = wvg + u * 16;          // 0..255
        int src = map[rr];
        float v = xo_pre[(size_t)(base + src) * D + d];
        v = (v - mu) * rs * gm + bt;
        v = (v > 0.f) ? kScale * v : kScale * kAlpha * expm1f(v);
        out[(size_t)(b * N_HALF + half * KPOOL + rr) * D + d] = v * sc_s[src];
    }
}

extern "C" void kernel_launch(void* const* d_in, const int* in_sizes, int n_in,
                              void* d_out, int out_size, void* d_ws, size_t ws_size,
                              hipStream_t stream) {
    const float* x1   = (const float*)d_in[0];
    const float* x2   = (const float*)d_in[1];
    const float* W1   = (const float*)d_in[2];
    const float* b1   = (const float*)d_in[3];
    const float* W2   = (const float*)d_in[4];
    const float* b2   = (const float*)d_in[5];
    const float* Wa   = (const float*)d_in[6];
    const float* ba   = (const float*)d_in[7];
    const float* w11  = (const float*)d_in[10];
    const float* w22  = (const float*)d_in[11];
    const float* w12  = (const float*)d_in[12];
    const float* Wpa  = (const float*)d_in[14];
    const float* bpa  = (const float*)d_in[15];
    const float* Wwoa = (const float*)d_in[16];
    const float* bwoa = (const float*)d_in[17];
    const float* gamma= (const float*)d_in[22];
    const float* beta = (const float*)d_in[23];
    const float* Wp   = (const float*)d_in[24];
    const float* bp   = (const float*)d_in[25];
    float* out = (float*)d_out;

    char* ws = (char*)d_ws;
    float*          x_f     = (float*)(ws + 0);                  // 524288
    unsigned short* x_bf    = (unsigned short*)(ws + 524288);    // 262144
    unsigned short* xT_hi   = (unsigned short*)(ws + 786432);    // 262144
    unsigned short* xT_lo   = (unsigned short*)(ws + 1048576);   // 262144
    unsigned*       Ep      = (unsigned*)(ws + 1310720);         // 8388608
    float*          pagg    = (float*)(ws + 9699328);            // 1048576
    float*          rowsum  = (float*)(ws + 10747904);           // 16384
    float*          xo_pre  = (float*)(ws + 10764288);           // 524288
    float*          partials= (float*)(ws + 11288576);           // 65536

    hipLaunchKernelGGL(k_proj, dim3(512), dim3(64), 0, stream,
                       x1, x2, W1, b1, W2, b2, x_f, x_bf, xT_hi, xT_lo);
    hipLaunchKernelGGL(k_score, dim3(2048), dim3(256), 0, stream,
                       x_f, x_bf, Wa, ba, w11, w22, w12, Ep);
    hipLaunchKernelGGL(k_aggp, dim3(256), dim3(256), 0, stream,
                       Ep, xT_hi, xT_lo, pagg, rowsum);
    hipLaunchKernelGGL(k_aggfin, dim3(128), dim3(256), 0, stream,
                       pagg, rowsum, x_f, Wpa, bpa, Wwoa, bwoa, xo_pre, partials);
    hipLaunchKernelGGL(k_tail, dim3(4), dim3(1024), 0, stream,
                       xo_pre, partials, gamma, beta, Wp, bp, out);
}

// Round 15
// 84.300 us; speedup vs baseline: 1.2710x; 1.2710x over previous
//
#include <hip/hip_runtime.h>

typedef float f32x4 __attribute__((ext_vector_type(4)));
typedef short short8 __attribute__((ext_vector_type(8)));
typedef short s16x4 __attribute__((ext_vector_type(4)));

#define N_TOT 1024
#define N_HALF 512
#define D 64
#define KPOOL 256

#if __has_builtin(__builtin_amdgcn_exp2f)
#define EXP2F(x) __builtin_amdgcn_exp2f(x)
#else
#define EXP2F(x) __expf((x) * 0.6931471805599453f)
#endif
#if __has_builtin(__builtin_amdgcn_rcpf)
#define RCPF(x) __builtin_amdgcn_rcpf(x)
#else
#define RCPF(x) (1.0f / (x))
#endif

__device__ __forceinline__ short f2bf(float v) {
    unsigned u = __float_as_uint(v);
    u += 0x7FFFu + ((u >> 16) & 1u);   // round-to-nearest-even
    return (short)(u >> 16);
}
__device__ __forceinline__ float bf2f(unsigned short u) {
    return __uint_as_float(((unsigned)u) << 16);
}

// ---------------- Kernel 1: x = concat(x1@W1+b1, x2@W2+b2); 4 rows/block, vectorized xT writes
__global__ void __launch_bounds__(64)
k_proj(const float* __restrict__ x1, const float* __restrict__ x2,
       const float* __restrict__ W1, const float* __restrict__ b1,
       const float* __restrict__ W2, const float* __restrict__ b2,
       float* __restrict__ x_f, unsigned short* __restrict__ x_bf,
       unsigned short* __restrict__ xT_hi, unsigned short* __restrict__ xT_lo) {
    int blk = blockIdx.x;             // 512 = b(2) x 256 row-groups of 4
    int b = blk >> 8;
    int n0 = (blk & 255) * 4;
    int t = threadIdx.x;

    const float *src, *W, *bias;
    if (n0 < N_HALF) { src = x1 + (b * N_HALF + n0) * D;            W = W1; bias = b1; }
    else             { src = x2 + (b * N_HALF + (n0 - N_HALF)) * D; W = W2; bias = b2; }

    __shared__ float rows[4][D];
#pragma unroll
    for (int r = 0; r < 4; ++r) rows[r][t] = src[r * D + t];
    __syncthreads();

    float bv = bias[t];
    float acc[4];
#pragma unroll
    for (int r = 0; r < 4; ++r) acc[r] = bv;
    for (int d = 0; d < D; ++d) {
        float w = W[d * D + t];
#pragma unroll
        for (int r = 0; r < 4; ++r) acc[r] = fmaf(rows[r][d], w, acc[r]);
    }

    s16x4 hiv, lov;
#pragma unroll
    for (int r = 0; r < 4; ++r) {
        unsigned short hi = (unsigned short)f2bf(acc[r]);
        unsigned short lo = (unsigned short)f2bf(acc[r] - bf2f(hi));
        x_f[((size_t)b * N_TOT + n0 + r) * D + t] = acc[r];
        x_bf[((size_t)b * N_TOT + n0 + r) * D + t] = hi;
        hiv[r] = (short)hi; lov[r] = (short)lo;
    }
    *reinterpret_cast<s16x4*>(xT_hi + ((size_t)b * D + t) * N_TOT + n0) = hiv;
    *reinterpret_cast<s16x4*>(xT_lo + ((size_t)b * D + t) * N_TOT + n0) = lov;
}

// ---------------- Kernel 2: scores, upper triangle only (s symmetric), E packed (hi<<16|lo)
// grid 2048, work-balance swizzle; bias pre-loaded into MFMA accumulator, C2 folded into bfrag
__global__ void __launch_bounds__(256)
k_score(const float* __restrict__ x_f, const unsigned short* __restrict__ x_bf,
        const float* __restrict__ Wa, const float* __restrict__ ba,
        const float* __restrict__ w11, const float* __restrict__ w22,
        const float* __restrict__ w12, unsigned* __restrict__ Ep) {
    int bid = blockIdx.x;             // 0..2047
    int b = bid >> 10, n = bid & 1023;
    int q = n >> 8, c = n & 255;
    int i = (q << 8) | ((q & 1) ? (255 - c) : c);
    int tid = threadIdx.x;
    int l = tid & 63, wv = tid >> 6;
    int kc = l & 15, dg = l >> 4;

    __shared__ float xi_s[D];
    if (tid < D) xi_s[tid] = x_f[(b * N_TOT + i) * D + tid];
    __syncthreads();

    const float C2 = 2.885390081777927f;      // 2*log2(e)
    const float LOG2E = 1.4426950408889634f;

    const float* wTop = (i < N_HALF) ? w11 : w12;   // weight when j < 512
    const float* wBot = (i < N_HALF) ? w12 : w22;   // weight when j >= 512

    // B fragments: B[d][k] = x_i[d] * Wa[d][k] * C2 in bf16 (C2 folded);
    // MFMA accumulator initialized with ba[k]*C2 -> exp2(acc) directly.
    short8 bfrag[4][2];
    f32x4 accinit[4];
    float wm2A[4], wm2B[4];
    float wsumA = 0.f, wsumB = 0.f;
#pragma unroll
    for (int kt = 0; kt < 4; ++kt) {
        int kcol = kt * 16 + kc;
        float bac = ba[kcol] * C2;
        accinit[kt] = {bac, bac, bac, bac};   // col = kc constant per lane
        float wA = wTop[kcol], wB = wBot[kcol];
        wm2A[kt] = -2.f * wA; wm2B[kt] = -2.f * wB;
        wsumA += wA; wsumB += wB;
#pragma unroll
        for (int mm = 0; mm < 2; ++mm) {
            short8 f;
#pragma unroll
            for (int e = 0; e < 8; ++e) {
                int d = mm * 32 + dg * 8 + e;
                f[e] = f2bf(xi_s[d] * Wa[d * D + kcol] * C2);
            }
            bfrag[kt][mm] = f;
        }
    }

    const unsigned short* xb_b = x_bf + b * N_TOT * D;
    unsigned* Eb = Ep + ((size_t)b << 20);
    int jt0 = i >> 4;
    for (int jt = jt0 + wv; jt < 64; jt += 4) {
        const unsigned short* arow = xb_b + (jt * 16 + kc) * D + dg * 8;
        short8 a0 = *reinterpret_cast<const short8*>(arow);
        short8 a1 = *reinterpret_cast<const short8*>(arow + 32);
        f32x4 acc[4];
#pragma unroll
        for (int kt = 0; kt < 4; ++kt) {
            f32x4 z = accinit[kt];
            z = __builtin_amdgcn_mfma_f32_16x16x32_bf16(a0, bfrag[kt][0], z, 0, 0, 0);
            z = __builtin_amdgcn_mfma_f32_16x16x32_bf16(a1, bfrag[kt][1], z, 0, 0, 0);
            acc[kt] = z;
        }
        bool top = (jt < 32);
        float wsum_t = top ? wsumA : wsumB;
        float wm2s[4];
#pragma unroll
        for (int kt = 0; kt < 4; ++kt) wm2s[kt] = top ? wm2A[kt] : wm2B[kt];
#pragma unroll
        for (int r = 0; r < 4; ++r) {
            float part = wsum_t;
#pragma unroll
            for (int kt = 0; kt < 4; ++kt) {
                float e2 = EXP2F(acc[kt][r]);
                float rcv = RCPF(e2 + 1.f);
                part = fmaf(wm2s[kt], rcv, part);
            }
            part += __shfl_xor(part, 1);
            part += __shfl_xor(part, 2);
            part += __shfl_xor(part, 4);
            part += __shfl_xor(part, 8);
            if (kc == 0) {
                int j = jt * 16 + dg * 4 + r;
                if (j >= i) {
                    float e = EXP2F(part * LOG2E);   // |s| <= sum|w| ~ 10, no max-shift
                    unsigned short eh = (unsigned short)f2bf(e);
                    unsigned short el = (unsigned short)f2bf(e - bf2f(eh));
                    unsigned pk = ((unsigned)eh << 16) | (unsigned)el;
                    Eb[(size_t)i * N_TOT + j] = pk;
                    if (j > i) Eb[(size_t)j * N_TOT + i] = pk;
                }
            }
        }
    }
}

// ---------------- Kernel 3: partial agg via hi/lo MFMA over j-halves of 512, + rowsum partials
__global__ void __launch_bounds__(256)
k_aggp(const unsigned* __restrict__ Ep,
       const unsigned short* __restrict__ xT_hi, const unsigned short* __restrict__ xT_lo,
       float* __restrict__ pagg, float* __restrict__ rowsum_part) {
    int blk = blockIdx.x;             // 256 = b(2) x it(64) x jh(2)
    int b = blk >> 7, rest = blk & 127;
    int it = rest >> 1, jh = rest & 1;
    int i0 = it * 16, jbase = jh * 512;
    int tid = threadIdx.x;
    int l = tid & 63, wv = tid >> 6;
    int kc = l & 15, dg = l >> 4;

    const unsigned* Eb = Ep + ((size_t)b << 20);
    const unsigned short* xTH = xT_hi + (size_t)b * D * N_TOT;
    const unsigned short* xTL = xT_lo + (size_t)b * D * N_TOT;

    f32x4 C0 = {0.f, 0.f, 0.f, 0.f}, C1 = C0, C2v = C0;
    const unsigned* Ap = Eb + (size_t)(i0 + kc) * N_TOT + jbase + dg * 8;
    const unsigned short* BH = xTH + (size_t)(wv * 16 + kc) * N_TOT + jbase + dg * 8;
    const unsigned short* BL = xTL + (size_t)(wv * 16 + kc) * N_TOT + jbase + dg * 8;
#pragma unroll 4
    for (int ks = 0; ks < 16; ++ks) {
        uint4 p0 = *reinterpret_cast<const uint4*>(Ap + ks * 32);
        uint4 p1 = *reinterpret_cast<const uint4*>(Ap + ks * 32 + 4);
        short8 ah, al;
        ah[0] = (short)(p0.x >> 16); al[0] = (short)(p0.x & 0xffff);
        ah[1] = (short)(p0.y >> 16); al[1] = (short)(p0.y & 0xffff);
        ah[2] = (short)(p0.z >> 16); al[2] = (short)(p0.z & 0xffff);
        ah[3] = (short)(p0.w >> 16); al[3] = (short)(p0.w & 0xffff);
        ah[4] = (short)(p1.x >> 16); al[4] = (short)(p1.x & 0xffff);
        ah[5] = (short)(p1.y >> 16); al[5] = (short)(p1.y & 0xffff);
        ah[6] = (short)(p1.z >> 16); al[6] = (short)(p1.z & 0xffff);
        ah[7] = (short)(p1.w >> 16); al[7] = (short)(p1.w & 0xffff);
        short8 bh = *reinterpret_cast<const short8*>(BH + ks * 32);
        short8 bl = *reinterpret_cast<const short8*>(BL + ks * 32);
        C0 = __builtin_amdgcn_mfma_f32_16x16x32_bf16(ah, bh, C0, 0, 0, 0);
        C1 = __builtin_amdgcn_mfma_f32_16x16x32_bf16(ah, bl, C1, 0, 0, 0);
        C2v = __builtin_amdgcn_mfma_f32_16x16x32_bf16(al, bh, C2v, 0, 0, 0);
    }
    f32x4 C = (C0 + C1) + C2v;

    // rowsum partial: wave wv rows wv*4..wv*4+3, 16 segs of 32 j, both halves of packed
    {
        int row = wv * 4 + (l & 3);
        int seg = l >> 2;
        const unsigned* Er = Eb + (size_t)(i0 + row) * N_TOT + jbase + seg * 32;
        float rs = 0.f;
#pragma unroll
        for (int u = 0; u < 8; ++u) {
            uint4 v = *reinterpret_cast<const uint4*>(Er + u * 4);
            rs += __uint_as_float(v.x & 0xffff0000u) + __uint_as_float(v.x << 16);
            rs += __uint_as_float(v.y & 0xffff0000u) + __uint_as_float(v.y << 16);
            rs += __uint_as_float(v.z & 0xffff0000u) + __uint_as_float(v.z << 16);
            rs += __uint_as_float(v.w & 0xffff0000u) + __uint_as_float(v.w << 16);
        }
        rs += __shfl_xor(rs, 4);
        rs += __shfl_xor(rs, 8);
        rs += __shfl_xor(rs, 16);
        rs += __shfl_xor(rs, 32);
        if (l < 4) rowsum_part[(size_t)(b * 2 + jh) * N_TOT + i0 + wv * 4 + l] = rs;
    }

#pragma unroll
    for (int r = 0; r < 4; ++r)
        pagg[((size_t)(b * 2 + jh) * N_TOT + i0 + dg * 4 + r) * D + wv * 16 + kc] = C[r];
}

// ---------------- Kernel 4: finish agg (+rinv), xo = agg@Wpa + x@Wwoa + biases, BN partials
__global__ void __launch_bounds__(256)
k_aggfin(const float* __restrict__ pagg, const float* __restrict__ rowsum_part,
         const float* __restrict__ x_f,
         const float* __restrict__ Wpa, const float* __restrict__ bpa,
         const float* __restrict__ Wwoa, const float* __restrict__ bwoa,
         float* __restrict__ xo_pre, float* __restrict__ partials) {
    int b = blockIdx.x >> 6, it = blockIdx.x & 63;
    int i0 = it * 16;
    int tid = threadIdx.x;
    int l = tid & 63, wv = tid >> 6;

    __shared__ float aggL[16][D];
    __shared__ float xiL[16][D];
    __shared__ float xoL[16][D];
    __shared__ float riL[16];

    const float* p0 = pagg + ((size_t)(b * 2 + 0) * N_TOT + i0) * D;
    const float* p1 = pagg + ((size_t)(b * 2 + 1) * N_TOT + i0) * D;
    const float* xB = x_f + ((size_t)b * N_TOT + i0) * D;
#pragma unroll
    for (int u = 0; u < 4; ++u) {
        int idx = tid + u * 256;       // 0..1023 = row*64+k
        reinterpret_cast<float*>(aggL)[idx] = p0[idx] + p1[idx];
        reinterpret_cast<float*>(xiL)[idx] = xB[idx];
    }
    if (tid < 16)
        riL[tid] = 1.f / (rowsum_part[(size_t)(b * 2 + 0) * N_TOT + i0 + tid] +
                          rowsum_part[(size_t)(b * 2 + 1) * N_TOT + i0 + tid]);
    __syncthreads();
#pragma unroll
    for (int u = 0; u < 4; ++u) {
        int idx = tid + u * 256;
        reinterpret_cast<float*>(aggL)[idx] *= riL[idx >> 6];
    }
    __syncthreads();

    int k = l;
    float xo[4];
#pragma unroll
    for (int r = 0; r < 4; ++r) xo[r] = bpa[k] + bwoa[k];
    for (int dd = 0; dd < D; ++dd) {
        float wp = Wpa[dd * D + k], ww = Wwoa[dd * D + k];
#pragma unroll
        for (int r = 0; r < 4; ++r) {
            int row = wv * 4 + r;
            xo[r] += aggL[row][dd] * wp + xiL[row][dd] * ww;
        }
    }
#pragma unroll
    for (int r = 0; r < 4; ++r) {
        int row = wv * 4 + r;
        xo_pre[((size_t)b * N_TOT + i0 + row) * D + k] = xo[r];
        xoL[row][k] = xo[r];
    }
    __syncthreads();
    if (tid < D) {
        float s = 0.f, qv = 0.f;
#pragma unroll
        for (int mm = 0; mm < 16; ++mm) { float v = xoL[mm][tid]; s += v; qv = fmaf(v, v, qv); }
        partials[blockIdx.x * 128 + tid] = s;
        partials[blockIdx.x * 128 + 64 + tid] = qv;
    }
}

// ---------------- Kernel 5: finish BN stats (128 partial blocks)
__global__ void k_stats2(const float* __restrict__ partials, float* __restrict__ stats) {
    int t = threadIdx.x;            // 512
    int g = t >> 7;                 // 0..3 : 32 blocks each
    int f128 = t & 127;
    float s = 0.f;
    for (int blk = g * 32; blk < g * 32 + 32; ++blk) s += partials[blk * 128 + f128];
    __shared__ float SQ[4][128];
    SQ[g][f128] = s;
    __syncthreads();
    if (t < 128) {
        float tot = SQ[0][t] + SQ[1][t] + SQ[2][t] + SQ[3][t];
        SQ[0][t] = tot;
    }
    __syncthreads();
    if (t < D) {
        float mu = SQ[0][t] * (1.f / 2048.f);
        float ex2 = SQ[0][64 + t] * (1.f / 2048.f);
        stats[t] = mu;
        stats[D + t] = rsqrtf(ex2 - mu * mu + 1e-5f);
    }
}

// ---------------- Kernel 6: BN + SELU + pool scores (4 rows/block)
__global__ void k_norm(const float* __restrict__ xo_pre, const float* __restrict__ stats,
                       const float* __restrict__ gamma, const float* __restrict__ beta,
                       const float* __restrict__ Wp, const float* __restrict__ bp,
                       float* __restrict__ o_norm, float* __restrict__ scores) {
    int r = blockIdx.x * 4 + (threadIdx.x >> 6);  // 0..2047
    int t = threadIdx.x & 63;
    float v = xo_pre[r * D + t];
    v = (v - stats[t]) * stats[D + t] * gamma[t] + beta[t];
    const float kScale = 1.0507009873554805f, kAlpha = 1.6732632423543772f;
    v = (v > 0.f) ? kScale * v : kScale * kAlpha * expm1f(v);
    o_norm[r * D + t] = v;
    float pd = v * Wp[t];
#pragma unroll
    for (int off = 32; off >= 1; off >>= 1) pd += __shfl_xor(pd, off);
    if (t == 0) scores[r] = 1.f / (1.f + __expf(-(pd + bp[0])));
}

// ---------------- Kernel 7: top-k (k=256) via exact ranking + gather (512 threads)
__global__ void __launch_bounds__(512)
k_pool(const float* __restrict__ o_norm, const float* __restrict__ scores,
       float* __restrict__ out) {
    int b = blockIdx.x >> 1, half = blockIdx.x & 1;
    int tid = threadIdx.x;          // 512
    __shared__ float sc_s[N_HALF];
    __shared__ unsigned long long keys[N_HALF];
    __shared__ unsigned short map[KPOOL];

    {
        float sc = scores[b * N_TOT + half * N_HALF + tid];
        sc_s[tid] = sc;
        // sigmoid > 0 -> float bits monotone as uint; ties: smaller idx wins
        keys[tid] = ((unsigned long long)__float_as_uint(sc) << 10) | (unsigned)(511 - tid);
    }
    __syncthreads();
    unsigned long long mine = keys[tid];
    int cnt = 0;
#pragma unroll 8
    for (int qq = 0; qq < N_HALF; ++qq) cnt += (keys[qq] > mine) ? 1 : 0;
    if (cnt < KPOOL) map[cnt] = (unsigned short)tid;
    __syncthreads();
    int d = tid & 63;
    for (int rr = tid >> 6; rr < KPOOL; rr += 8) {
        int src = map[rr];
        out[(size_t)(b * N_HALF + half * KPOOL + rr) * D + d] =
            o_norm[(size_t)(b * N_TOT + half * N_HALF + src) * D + d] * sc_s[src];
    }
}

extern "C" void kernel_launch(void* const* d_in, const int* in_sizes, int n_in,
                              void* d_out, int out_size, void* d_ws, size_t ws_size,
                              hipStream_t stream) {
    const float* x1   = (const float*)d_in[0];
    const float* x2   = (const float*)d_in[1];
    const float* W1   = (const float*)d_in[2];
    const float* b1   = (const float*)d_in[3];
    const float* W2   = (const float*)d_in[4];
    const float* b2   = (const float*)d_in[5];
    const float* Wa   = (const float*)d_in[6];
    const float* ba   = (const float*)d_in[7];
    const float* w11  = (const float*)d_in[10];
    const float* w22  = (const float*)d_in[11];
    const float* w12  = (const float*)d_in[12];
    const float* Wpa  = (const float*)d_in[14];
    const float* bpa  = (const float*)d_in[15];
    const float* Wwoa = (const float*)d_in[16];
    const float* bwoa = (const float*)d_in[17];
    const float* gamma= (const float*)d_in[22];
    const float* beta = (const float*)d_in[23];
    const float* Wp   = (const float*)d_in[24];
    const float* bp   = (const float*)d_in[25];
    float* out = (float*)d_out;

    char* ws = (char*)d_ws;
    float*          x_f     = (float*)(ws + 0);                  // 524288
    unsigned short* x_bf    = (unsigned short*)(ws + 524288);    // 262144
    unsigned short* xT_hi   = (unsigned short*)(ws + 786432);    // 262144
    unsigned short* xT_lo   = (unsigned short*)(ws + 1048576);   // 262144
    unsigned*       Ep      = (unsigned*)(ws + 1310720);         // 8388608
    float*          pagg    = (float*)(ws + 9699328);            // 1048576
    float*          rowsum  = (float*)(ws + 10747904);           // 16384
    float*          xo_pre  = (float*)(ws + 10764288);           // 524288
    float*          o_norm  = (float*)(ws + 11288576);           // 524288
    float*          scores  = (float*)(ws + 11812864);           // 8192
    float*          partials= (float*)(ws + 11821056);           // 65536
    float*          stats   = (float*)(ws + 11886592);           // 512

    hipLaunchKernelGGL(k_proj, dim3(512), dim3(64), 0, stream,
                       x1, x2, W1, b1, W2, b2, x_f, x_bf, xT_hi, xT_lo);
    hipLaunchKernelGGL(k_score, dim3(2048), dim3(256), 0, stream,
                       x_f, x_bf, Wa, ba, w11, w22, w12, Ep);
    hipLaunchKernelGGL(k_aggp, dim3(256), dim3(256), 0, stream,
                       Ep, xT_hi, xT_lo, pagg, rowsum);
    hipLaunchKernelGGL(k_aggfin, dim3(128), dim3(256), 0, stream,
                       pagg, rowsum, x_f, Wpa, bpa, Wwoa, bwoa, xo_pre, partials);
    hipLaunchKernelGGL(k_stats2, dim3(1), dim3(512), 0, stream, partials, stats);
    hipLaunchKernelGGL(k_norm, dim3(512), dim3(256), 0, stream,
                       xo_pre, stats, gamma, beta, Wp, bp, o_norm, scores);
    hipLaunchKernelGGL(k_pool, dim3(4), dim3(512), 0, stream, o_norm, scores, out);
}